// Round 5
// baseline (115.347 us; speedup 1.0000x reference)
//
#include <hip/hip_runtime.h>
#include <stdint.h>

// BCM_Linear: out = x @ W^T, W[o,k] = w[o>>6, k>>6, (o-k)&63]  (1024x1024)
// M=32768, N=1024, K=1024. bf16 MFMA compute, fp32 in/out.
// Round 5: round-4's 128x128/512t/2-blocks-per-CU structure + FUSED fp32->bf16
// A-conversion (reg-stage: 4x global_load_dwordx4 -> cvt -> swizzled ds_write).
// B via pre-swizzled bf16 Wb + global_load_lds. No separate cvt_x pass.

#define NTOK 32768
#define NCH  1024
#define BK   64
#define NKT  (NCH / BK)   // 16

typedef short bf16x8 __attribute__((ext_vector_type(8)));
typedef float f32x4  __attribute__((ext_vector_type(4)));
typedef unsigned short u16x8 __attribute__((ext_vector_type(8)));

static __device__ __forceinline__ unsigned short f2bf(float f) {
    unsigned int u = __float_as_uint(f);
    u += 0x7FFFu + ((u >> 16) & 1u);
    return (unsigned short)(u >> 16);
}

static __device__ __forceinline__ u16x8 pack8(float4 a, float4 b) {
    u16x8 v;
    v[0]=f2bf(a.x); v[1]=f2bf(a.y); v[2]=f2bf(a.z); v[3]=f2bf(a.w);
    v[4]=f2bf(b.x); v[5]=f2bf(b.y); v[6]=f2bf(b.z); v[7]=f2bf(b.w);
    return v;
}

#define GLOAD16(gp, lp)                                                          \
    __builtin_amdgcn_global_load_lds(                                            \
        (const __attribute__((address_space(1))) unsigned int*)(gp),             \
        (__attribute__((address_space(3))) unsigned int*)(lp), 16, 0, 0)

// ---------------- kernel 1: circulant w -> dense bf16 W, pre-swizzled (proven) ----------------
__global__ void build_w_kernel(const float* __restrict__ w, unsigned short* __restrict__ Wb) {
    int i = blockIdx.x * blockDim.x + threadIdx.x;   // 0 .. 1024*128-1
    int o = i >> 7;
    int j = i & 127;
    int r = o >> 6;
    int q = j >> 3;
    const float* wrow = w + ((r * 16 + q) << 6);
    int k0 = j << 3;
    u16x8 v;
#pragma unroll
    for (int e = 0; e < 8; ++e) v[e] = f2bf(wrow[(o - (k0 + e)) & 63]);
    int js = (j & ~7) | ((j & 7) ^ (o & 7));
    *(u16x8*)(Wb + (((size_t)o) << 10) + (js << 3)) = v;
}

// ---------------- kernel 2: 128x128 fused GEMM, 2 blocks/CU ----------------
#define PHASE_BAR() __builtin_amdgcn_s_barrier()
#define LGKM0() asm volatile("s_waitcnt lgkmcnt(0)" ::: "memory")
#define VMCNT(n) asm volatile("s_waitcnt vmcnt(" #n ")" ::: "memory")
#define CFENCE() asm volatile("" ::: "memory")
#define SETPRIO(n) __builtin_amdgcn_s_setprio(n)
#define MFMA4(d, av, bv) d = __builtin_amdgcn_mfma_f32_16x16x32_bf16(av, bv, d, 0, 0, 0)

// A issue: 16 consecutive fp32 of one row (tid>>2), col chunk (tid&3)*16 + t*64.
#define ISSUE_A(t) do {                                                          \
    const float4* _p = (const float4*)(pA + ((t) << 6));                         \
    areg[0] = _p[0]; areg[1] = _p[1]; areg[2] = _p[2]; areg[3] = _p[3];          \
    CFENCE();                                                                    \
} while (0)

// A write: cvt 16 floats -> 2 swizzled ds_write_b128.
#define WRITE_A(Abuf) do {                                                       \
    u16x8 _w0 = pack8(areg[0], areg[1]);                                         \
    u16x8 _w1 = pack8(areg[2], areg[3]);                                         \
    *(u16x8*)((Abuf) + aw0) = _w0;                                               \
    *(u16x8*)((Abuf) + aw1) = _w1;                                               \
    CFENCE();                                                                    \
} while (0)

// B staging: 128 rows x 64 cols bf16 = 16 KB, 2 gload16/thread.
#define STAGE_B(buf, t) do {                                                     \
    const char* _s = srcB + ((t) << 7);                                          \
    char* _d = (buf) + (wv << 10);                                               \
    GLOAD16(_s, _d); GLOAD16(_s + (64 << 11), _d + 8192);                        \
} while (0)

// frag reads + MFMA for one K-tile
#define KCOMPUTE(Abuf, Bbuf) do {                                                \
    bf16x8 afr[4][2], bfr[2][2];                                                 \
    _Pragma("unroll") for (int m = 0; m < 4; ++m)                                \
      _Pragma("unroll") for (int ks = 0; ks < 2; ++ks)                           \
        afr[m][ks] = *(const bf16x8*)((Abuf) + a_off[ks] + m * 2048);            \
    _Pragma("unroll") for (int n = 0; n < 2; ++n)                                \
      _Pragma("unroll") for (int ks = 0; ks < 2; ++ks)                           \
        bfr[n][ks] = *(const bf16x8*)((Bbuf) + b_off[ks] + n * 2048);            \
    LGKM0();                                                                     \
    SETPRIO(1);                                                                  \
    _Pragma("unroll") for (int m = 0; m < 4; ++m)                                \
      _Pragma("unroll") for (int n = 0; n < 2; ++n) {                            \
        MFMA4(acc[m][n], afr[m][0], bfr[n][0]);                                  \
        MFMA4(acc[m][n], afr[m][1], bfr[n][1]);                                  \
      }                                                                          \
    SETPRIO(0);                                                                  \
} while (0)

__global__ void __launch_bounds__(512, 4) gemm_fused_kernel(const float* __restrict__ X,
                                                            const unsigned short* __restrict__ B,
                                                            float* __restrict__ C) {
    __shared__ __align__(16) char lds[65536];
    char* As0 = lds;                 // 128 rows x 128 B bf16
    char* As1 = lds + 16384;
    char* Bs0 = lds + 32768;
    char* Bs1 = lds + 49152;

    int tid  = threadIdx.x;
    int lane = tid & 63;
    int wv   = tid >> 6;       // 0..7
    int wr   = wv >> 2;        // 0..1  (M: 2 x 64 rows)
    int wc   = wv & 3;         // 0..3  (N: 4 x 32 cols)

    // T1: XCD-chunked swizzle; 2048 blocks, cpx=256; tn fast -> the 8 blocks
    // sharing one A-panel are consecutive wid -> same XCD -> x panel L2-hot.
    int cpx = gridDim.x >> 3;
    int wid = ((int)blockIdx.x & 7) * cpx + ((int)blockIdx.x >> 3);
    int tn = wid & 7, tm = wid >> 3;
    int m0 = tm * 128, n0 = tn * 128;

    // A source: raw fp32 x; row = m0 + tid>>2, 16 consecutive floats at (tid&3)*16.
    const float* pA = X + ((size_t)(m0 + (tid >> 2)) << 10) + ((tid & 3) << 4);
    float4 areg[4];

    // A LDS write offsets (st-swizzle, round-3-proven): row*128 + 16*(blk ^ (row&7))
    int wrow = tid >> 2;
    int j0   = (tid & 3) << 1;
    int r7   = wrow & 7;
    int aw0  = wrow * 128 + (((j0    ) ^ r7) << 4);
    int aw1  = wrow * 128 + (((j0 + 1) ^ r7) << 4);

    // B staging source (pre-swizzled Wb -> linear gather)
    const char* srcB = (const char*)B + (((size_t)(n0 + (tid >> 3))) << 11) + ((tid & 7) << 4);

    // T2 swizzled ds_read offsets (round-2/4-proven)
    int xa   = (lane & 7) << 4;
    int kq16 = (lane >> 4) << 4;
    int abase = (wr * 64 + (lane & 15)) * 128;
    int bbase = (wc * 32 + (lane & 15)) * 128;
    int a_off[2] = { abase + (kq16 ^ xa), abase + ((64 + kq16) ^ xa) };
    int b_off[2] = { bbase + (kq16 ^ xa), bbase + ((64 + kq16) ^ xa) };

    f32x4 acc[4][2] = {};

    // ---- prologue: tile 0 ----
    ISSUE_A(0); STAGE_B(Bs0, 0);     // vmem order: A0 x4, B0 x2
    VMCNT(2);                        // A0 regs ready
    WRITE_A(As0);
    VMCNT(0); LGKM0();               // B0 in LDS, my A0 ds_writes drained
    PHASE_BAR();

    // ---- main loop ----
    for (int t = 0; t < NKT; t += 2) {
        // tile t (bufs 0): prefetch t+1 -> bufs 1 (t+1 <= 15 always)
        ISSUE_A(t + 1); STAGE_B(Bs1, t + 1);
        KCOMPUTE(As0, Bs0);
        VMCNT(2); WRITE_A(As1);
        VMCNT(0); LGKM0(); PHASE_BAR();
        if (t + 2 < NKT) {
            ISSUE_A(t + 2); STAGE_B(Bs0, t + 2);
            KCOMPUTE(As1, Bs1);
            VMCNT(2); WRITE_A(As0);
            VMCNT(0); LGKM0(); PHASE_BAR();
        } else {
            KCOMPUTE(As1, Bs1);      // last tile, no prefetch
        }
    }

    // epilogue: C/D layout col = lane&15, row = (lane>>4)*4 + j
    float* Cp = C + ((size_t)(m0 + wr * 64)) * NCH + n0 + wc * 32;
    int cc = lane & 15;
    int rr = (lane >> 4) << 2;
#pragma unroll
    for (int m = 0; m < 4; ++m)
#pragma unroll
        for (int j = 0; j < 4; ++j) {
            float* rowp = Cp + ((size_t)(m * 16 + rr + j)) * NCH;
#pragma unroll
            for (int n = 0; n < 2; ++n)
                rowp[n * 16 + cc] = acc[m][n][j];
        }
}

// ---------------- fallback (ws too small): naive fp32 ----------------
__global__ void naive_kernel(const float* __restrict__ x, const float* __restrict__ w,
                             float* __restrict__ out) {
    int t = blockIdx.x;
    int o = blockIdx.y * 256 + threadIdx.x;
    const float* xr = x + (size_t)t * NCH;
    int r = o >> 6, oi = o & 63;
    float s = 0.f;
    for (int q = 0; q < 16; ++q) {
        const float* wq = w + (r * 16 + q) * 64;
        const float* xq = xr + q * 64;
#pragma unroll 8
        for (int j = 0; j < 64; ++j) s += xq[j] * wq[(oi - j) & 63];
    }
    out[(size_t)t * NCH + o] = s;
}

extern "C" void kernel_launch(void* const* d_in, const int* in_sizes, int n_in,
                              void* d_out, int out_size, void* d_ws, size_t ws_size,
                              hipStream_t stream) {
    const float* x = (const float*)d_in[0];
    const float* w = (const float*)d_in[1];
    float* out = (float*)d_out;

    const size_t needW = (size_t)NCH * NCH * sizeof(unsigned short);   // 2 MB

    if (ws_size >= needW) {
        unsigned short* Wb = (unsigned short*)d_ws;
        hipLaunchKernelGGL(build_w_kernel, dim3(NCH * 128 / 256), dim3(256), 0, stream, w, Wb);
        hipLaunchKernelGGL(gemm_fused_kernel, dim3(2048), dim3(512), 0, stream, x, Wb, out);
    } else {
        hipLaunchKernelGGL(naive_kernel, dim3(NTOK, 4), dim3(256), 0, stream, x, w, out);
    }
}